// Round 3
// baseline (270.792 us; speedup 1.0000x reference)
//
#include <hip/hip_runtime.h>
#include <stdint.h>

#define MDIM 8192
#define NDIM 1536
#define KDIM 3072

#define BM 128
#define BN 128
#define BK 96            // three 32-k planes, each in the R2/R4-proven 64B-row swizzled layout

#define NMB ((KDIM / 64) * (NDIM / 64))
#define NCVT_BLOCKS 4096
#define CVT_PER_THREAD 6   // 4096*256*6 == MDIM*KDIM/4 exactly

typedef unsigned short u16;
typedef float  f32x4  __attribute__((ext_vector_type(4)));
typedef __bf16 bf16x8 __attribute__((ext_vector_type(8)));

__device__ __forceinline__ u16 f2bf(float f) {
    union { float f; unsigned int u; } v; v.f = f;
    unsigned int u = v.u;
    return (u16)((u + 0x7fffu + ((u >> 16) & 1u)) >> 16);  // RNE
}

// ---------------- fused prep: make_b blocks, then grid-stride cvt_x blocks ----------------
__global__ void prep_kernel(const float* __restrict__ w, const float* __restrict__ mask,
                            u16* __restrict__ Bt,
                            const float4* __restrict__ x, ushort4* __restrict__ xb) {
    const int t = threadIdx.x;
    if (blockIdx.x < NMB) {
        __shared__ float sw[64][65];
        const int kb = blockIdx.x % (KDIM / 64);
        const int nb = blockIdx.x / (KDIM / 64);
        const int k0 = kb * 64, n0 = nb * 64;
        {
            const int c4 = t & 15;
            const int r  = t >> 4;
#pragma unroll
            for (int rr = 0; rr < 4; ++rr) {
                int row = rr * 16 + r;
                float4 v = *(const float4*)&w[(size_t)(k0 + row) * NDIM + n0 + c4 * 4];
                sw[row][c4 * 4 + 0] = v.x;
                sw[row][c4 * 4 + 1] = v.y;
                sw[row][c4 * 4 + 2] = v.z;
                sw[row][c4 * 4 + 3] = v.w;
            }
        }
        __syncthreads();
        {
            const int n  = t >> 2;
            const int ks = (t & 3) * 16;
#pragma unroll
            for (int j = 0; j < 4; ++j) {
                int k = ks + j * 4;
                float4 mv = *(const float4*)&mask[(size_t)(n0 + n) * KDIM + k0 + k];
                ushort4 o;
                o.x = f2bf(mv.x * sw[k + 0][n]);
                o.y = f2bf(mv.y * sw[k + 1][n]);
                o.z = f2bf(mv.z * sw[k + 2][n]);
                o.w = f2bf(mv.w * sw[k + 3][n]);
                *(ushort4*)&Bt[(size_t)(n0 + n) * KDIM + k0 + k] = o;
            }
        }
    } else {
        // x f32 -> bf16: grid-stride, 6 independent float4 chains/thread for ILP,
        // consecutive threads -> consecutive float4s (fully coalesced each iter)
        const int base   = (blockIdx.x - NMB) * 256 + t;
        const int stride = NCVT_BLOCKS * 256;
#pragma unroll
        for (int j = 0; j < CVT_PER_THREAD; ++j) {
            int i = base + j * stride;
            float4 v = x[i];
            ushort4 o;
            o.x = f2bf(v.x); o.y = f2bf(v.y); o.z = f2bf(v.z); o.w = f2bf(v.w);
            xb[i] = o;
        }
    }
}

// ---------------- GEMM: C[m][n] = sum_k A[m][k]*Bt[n][k] + bias[n] ----------------
// Round-2 proven (77.4us): R0 structure + structured-zero K-skip:
//   mask p=0 blocks make Bt exactly 0 on: cls0 (n<512): k in [1024,1536)u[2560,3072);
//   cls2 (n>=1024): k in [0,512)u[1536,2048). Skip-class tiles run two 96-aligned
//   ranges of 11 steps (22 vs 32 steps).
// Slot-balanced dispatch: the 256 full-K tiles (bx 4..7) take bik 0..255 -> one per
// CU first-slot; 512 skip tiles fill slots 2-3. Per-CU work 32+22+22=76 step-units
// (== ideal 76). XCD by-band (by = xcd*8 + l) for L2 banding.
__device__ __forceinline__ void gload_lds16(const void* g, void* l) {
    __builtin_amdgcn_global_load_lds(
        (const __attribute__((address_space(1))) unsigned int*)g,
        (__attribute__((address_space(3))) unsigned int*)l, 16, 0, 0);
}

#define PLANE 4096   // u16 per k-plane (128 rows * 32)

__global__ void __launch_bounds__(256, 3)
gemm_kernel(const u16* __restrict__ A,   // [M][K] bf16
            const u16* __restrict__ B,   // [N][K] bf16
            const float* __restrict__ bias,
            float* __restrict__ C) {     // [M][N] fp32
    __shared__ u16 sA[3 * PLANE];  // 24 KiB
    __shared__ u16 sB[3 * PLANE];  // 24 KiB

    const int tid  = threadIdx.x;
    const int wave = tid >> 6;
    const int lane = tid & 63;

    // Balanced remap: bik<256 -> full-K tiles (bx 4..7); else skip tiles (bx 0..3,8..11).
    // Both groups keep XCD r -> by in [8r, 8r+8) for L2 banding.
    const int bik = blockIdx.x;
    int bx, by;
    if (bik < 256) {
        const int xcd = bik & 7, j = bik >> 3;   // j 0..31
        by = xcd * 8 + (j & 7);
        bx = 4 + (j >> 3);                        // 4..7
    } else {
        const int i = bik - 256, xcd = i & 7, j = i >> 3;  // j 0..63
        by = xcd * 8 + (j & 7);
        const int b = j >> 3;                     // 0..7
        bx = b < 4 ? b : b + 4;                   // 0..3, 8..11
    }
    const int m0 = by * BM, n0 = bx * BN;

    // k-range table by n-class (all bounds 96-aligned; supersets of nonzero support)
    const int cls  = bx >> 2;  // 0,1,2
    const int klo0 = cls == 0 ? 0    : (cls == 1 ? 0    : 480);
    const int khi0 = cls == 0 ? 1056 : (cls == 1 ? 3072 : 1536);
    const int klo1 = cls == 0 ? 1536 : (cls == 1 ? 3072 : 2016);
    const int khi1 = cls == 0 ? 2592 : (cls == 1 ? 3072 : 3072);

    const int srow = lane >> 2;
    const int scol = ((lane & 3) ^ ((lane >> 3) & 3)) * 8;

    const int wm = (wave >> 1) * 64;
    const int wn = (wave & 1) * 64;
    const int fr = lane & 15;
    const int fq = lane >> 4;
    const int fsw = (fq ^ ((fr >> 1) & 3)) * 8;

    f32x4 acc[4][4] = {};

    const u16* gA0 = A + (size_t)(m0 + wave * 16 + srow) * KDIM + scol;
    const u16* gB0 = B + (size_t)(n0 + wave * 16 + srow) * KDIM + scol;
    u16* lA0 = &sA[(wave * 16) * 32];
    u16* lA1 = &sA[(wave * 16 + 64) * 32];
    u16* lB0 = &sB[(wave * 16) * 32];
    u16* lB1 = &sB[(wave * 16 + 64) * 32];

#pragma unroll
    for (int seg = 0; seg < 2; ++seg) {
        const int klo = seg ? klo1 : klo0;
        const int khi = seg ? khi1 : khi0;
        for (int k0 = klo; k0 < khi; k0 += BK) {
            __syncthreads();
#pragma unroll
            for (int p = 0; p < 3; ++p) {
                gload_lds16(gA0 + k0 + p * 32,                      lA0 + p * PLANE);
                gload_lds16(gA0 + k0 + p * 32 + (size_t)64 * KDIM,  lA1 + p * PLANE);
                gload_lds16(gB0 + k0 + p * 32,                      lB0 + p * PLANE);
                gload_lds16(gB0 + k0 + p * 32 + (size_t)64 * KDIM,  lB1 + p * PLANE);
            }
            __syncthreads();

#pragma unroll
            for (int h = 0; h < 3; ++h) {
                const u16* pA = &sA[h * PLANE];
                const u16* pB = &sB[h * PLANE];
                bf16x8 af[4], bfv[4];
#pragma unroll
                for (int mt = 0; mt < 4; ++mt)
                    af[mt] = *(const bf16x8*)&pA[(wm + mt * 16 + fr) * 32 + fsw];
#pragma unroll
                for (int nt = 0; nt < 4; ++nt)
                    bfv[nt] = *(const bf16x8*)&pB[(wn + nt * 16 + fr) * 32 + fsw];
#pragma unroll
                for (int mt = 0; mt < 4; ++mt)
#pragma unroll
                    for (int nt = 0; nt < 4; ++nt)
                        acc[mt][nt] = __builtin_amdgcn_mfma_f32_16x16x32_bf16(
                            af[mt], bfv[nt], acc[mt][nt], 0, 0, 0);
            }
        }
    }

    // epilogue: C/D layout col = lane&15, row = (lane>>4)*4 + reg  [m89-verified]
#pragma unroll
    for (int nt = 0; nt < 4; ++nt) {
        int n = n0 + wn + nt * 16 + fr;
        float bv = bias[n];
#pragma unroll
        for (int mt = 0; mt < 4; ++mt) {
            int m = m0 + wm + mt * 16 + fq * 4;
#pragma unroll
            for (int r = 0; r < 4; ++r)
                C[(size_t)(m + r) * NDIM + n] = acc[mt][nt][r] + bv;
        }
    }
}

extern "C" void kernel_launch(void* const* d_in, const int* in_sizes, int n_in,
                              void* d_out, int out_size, void* d_ws, size_t ws_size,
                              hipStream_t stream) {
    const float* x    = (const float*)d_in[0];   // [8192][3072]
    const float* w    = (const float*)d_in[1];   // [3072][1536]
    const float* bias = (const float*)d_in[2];   // [1536]
    const float* mask = (const float*)d_in[3];   // [1536][3072]
    float* out = (float*)d_out;                  // [8192][1536]

    u16* xb = (u16*)d_ws;                                   // 50331648 B
    u16* Bt = (u16*)((char*)d_ws + (size_t)50331648);       //  9437184 B

    prep_kernel<<<NMB + NCVT_BLOCKS, 256, 0, stream>>>(w, mask, Bt, (const float4*)x, (ushort4*)xb);
    gemm_kernel<<<(MDIM / BM) * (NDIM / BN), 256, 0, stream>>>(xb, Bt, bias, out);
}

// Round 5
// 255.261 us; speedup vs baseline: 1.0608x; 1.0608x over previous
//
#include <hip/hip_runtime.h>
#include <stdint.h>

#define MDIM 8192
#define NDIM 1536
#define KDIM 3072

#define BM 256
#define BN 128
#define BK 64            // one K-tile = two 32-k planes in the proven swizzled layout
#define NGB ((MDIM / BM) * (NDIM / BN))   // 384 blocks

#define NMB ((KDIM / 64) * (NDIM / 64))
#define NCVT ((MDIM * KDIM / 4) / 256)

typedef unsigned short u16;
typedef float  f32x4  __attribute__((ext_vector_type(4)));
typedef __bf16 bf16x8 __attribute__((ext_vector_type(8)));

__device__ __forceinline__ u16 f2bf(float f) {
    union { float f; unsigned int u; } v; v.f = f;
    unsigned int u = v.u;
    return (u16)((u + 0x7fffu + ((u >> 16) & 1u)) >> 16);  // RNE
}

// ---------------- fused prep (R0/R2-proven): make_b blocks, then cvt_x blocks ----------------
__global__ void prep_kernel(const float* __restrict__ w, const float* __restrict__ mask,
                            u16* __restrict__ Bt,
                            const float4* __restrict__ x, ushort4* __restrict__ xb) {
    const int t = threadIdx.x;
    if (blockIdx.x < NMB) {
        __shared__ float sw[64][65];
        const int kb = blockIdx.x % (KDIM / 64);
        const int nb = blockIdx.x / (KDIM / 64);
        const int k0 = kb * 64, n0 = nb * 64;
        {
            const int c4 = t & 15;
            const int r  = t >> 4;
#pragma unroll
            for (int rr = 0; rr < 4; ++rr) {
                int row = rr * 16 + r;
                float4 v = *(const float4*)&w[(size_t)(k0 + row) * NDIM + n0 + c4 * 4];
                sw[row][c4 * 4 + 0] = v.x;
                sw[row][c4 * 4 + 1] = v.y;
                sw[row][c4 * 4 + 2] = v.z;
                sw[row][c4 * 4 + 3] = v.w;
            }
        }
        __syncthreads();
        {
            const int n  = t >> 2;
            const int ks = (t & 3) * 16;
#pragma unroll
            for (int j = 0; j < 4; ++j) {
                int k = ks + j * 4;
                float4 mv = *(const float4*)&mask[(size_t)(n0 + n) * KDIM + k0 + k];
                ushort4 o;
                o.x = f2bf(mv.x * sw[k + 0][n]);
                o.y = f2bf(mv.y * sw[k + 1][n]);
                o.z = f2bf(mv.z * sw[k + 2][n]);
                o.w = f2bf(mv.w * sw[k + 3][n]);
                *(ushort4*)&Bt[(size_t)(n0 + n) * KDIM + k0 + k] = o;
            }
        }
    } else {
        int i = (blockIdx.x - NMB) * 256 + t;
        float4 v = x[i];
        ushort4 o;
        o.x = f2bf(v.x); o.y = f2bf(v.y); o.z = f2bf(v.z); o.w = f2bf(v.w);
        xb[i] = o;
    }
}

// ---------------- GEMM: 8-phase counted-vmcnt template (T3+T4+T5), 256x128, 8 waves ----------------
// K-skip (exact, 64-aligned): cls0 (n<512): k in [0,1024)u[1536,2560); cls1: full;
// cls2 (n>=1024): [512,1536)u[2048,3072). Dispatch: 128 full-K blocks first, 256 skip
// blocks backfill (skip-CUs run 32+32 tiles vs full-CU 48). XCD banding by = xcd*4+l.
// Staging: 4 units/tile {B0:1, A0:2, B1:1, A1:2 gloads}, 1 unit/phase, each unit targets
// a plane fully consumed >=1 barrier earlier. vmcnt(4) before phase-4/8 closing barriers
// (= loads issued after the tile about to be computed). Raw s_barrier (no vmcnt-0 drain).
__device__ __forceinline__ void gload_lds16(const void* g, void* l) {
    __builtin_amdgcn_global_load_lds(
        (const __attribute__((address_space(1))) unsigned int*)g,
        (__attribute__((address_space(3))) unsigned int*)l, 16, 0, 0);
}

#define BARR  __builtin_amdgcn_s_barrier()
#define PRIO1 __builtin_amdgcn_s_setprio(1)
#define PRIO0 __builtin_amdgcn_s_setprio(0)
#define VM(n) asm volatile("s_waitcnt vmcnt(" #n ")" ::: "memory")

__global__ void __launch_bounds__(512, 2)
gemm_kernel(const u16* __restrict__ Ag,  // [M][K] bf16
            const u16* __restrict__ Bg,  // [N][K] bf16
            const float* __restrict__ bias,
            float* __restrict__ C) {     // [M][N] fp32
    extern __shared__ u16 smem[];        // 96 KiB: A 64K (4 planes x 256 x 32), B 32K
    u16* sAb = smem;                     // [(buf*2+plane)][256][32]
    u16* sBb = smem + 32768;             // [(buf*2+plane)][128][32]

    const int tid  = threadIdx.x;
    const int wv   = tid >> 6;           // 0..7
    const int lane = tid & 63;

    // ordering: bik 0..127 = full-K (bx 4..7), 128..383 = skip tiles; XCD r -> by in [4r,4r+4)
    const int bik = blockIdx.x;
    int bx, by;
    if (bik < 128) {
        by = (bik & 7) * 4 + ((bik >> 3) & 3);
        bx = 4 + (bik >> 5);
    } else {
        const int s = bik - 128;
        by = (s & 7) * 4 + ((s >> 3) & 3);
        const int r = s >> 5;            // 0..7
        bx = r < 4 ? r : r + 4;
    }
    const int m0 = by * BM, n0 = bx * BN;
    const int cls = bx >> 2;             // 0,1,2

    int ksplit, kb0, kb1, NT;
    if (cls == 1)      { ksplit = 48; kb0 = 0;   kb1 = 0;    NT = 48; }
    else if (cls == 0) { ksplit = 16; kb0 = 0;   kb1 = 1536; NT = 32; }
    else               { ksplit = 16; kb0 = 512; kb1 = 2048; NT = 32; }
    const int NI = NT >> 1;
    auto kof = [&](int i) { return i < ksplit ? kb0 + i * 64 : kb1 + (i - ksplit) * 64; };

    // staging addressing (proven plane-swizzle: source chunk xor, linear LDS dest)
    const int srow = lane >> 2;
    const int scol = ((lane & 3) ^ ((lane >> 3) & 3)) * 8;
    const u16* gA = Ag + (size_t)(m0 + wv * 16 + srow) * KDIM + scol;
    const u16* gB = Bg + (size_t)(n0 + wv * 16 + srow) * KDIM + scol;
    u16* dA0 = &sAb[(wv * 16) * 32];
    u16* dA1 = &sAb[(wv * 16 + 128) * 32];
    u16* dB  = &sBb[(wv * 16) * 32];

#define SA(b, p, ki) { gload_lds16(gA + (ki) + (p) * 32,                     dA0 + ((b) * 2 + (p)) * 8192); \
                       gload_lds16(gA + (ki) + (p) * 32 + (size_t)128 * KDIM, dA1 + ((b) * 2 + (p)) * 8192); }
#define SB(b, p, ki)   gload_lds16(gB + (ki) + (p) * 32,                     dB  + ((b) * 2 + (p)) * 4096);

    // fragment addressing (proven swizzle)
    const int wm = (wv >> 1) * 64;
    const int wn = (wv & 1) * 64;
    const int fr = lane & 15;
    const int fq = lane >> 4;
    const int fsw = (fq ^ ((fr >> 1) & 3)) * 8;

#define AFRAG(b, kk, mt) (*(const bf16x8*)&sAb[(((b) * 2 + (kk)) * 256 + wm + (mt) * 16 + fr) * 32 + fsw])
#define BFRAG(b, kk, nt) (*(const bf16x8*)&sBb[(((b) * 2 + (kk)) * 128 + wn + (nt) * 16 + fr) * 32 + fsw])
#define MF(mt, nt, xa, xb_) acc[mt][nt] = __builtin_amdgcn_mfma_f32_16x16x32_bf16(xa, xb_, acc[mt][nt], 0, 0, 0)
#define M8(mA, mB, xA, xB, b0_, b1_, b2_, b3_) \
    MF(mA, 0, xA, b0_); MF(mA, 1, xA, b1_); MF(mA, 2, xA, b2_); MF(mA, 3, xA, b3_); \
    MF(mB, 0, xB, b0_); MF(mB, 1, xB, b1_); MF(mB, 2, xB, b2_); MF(mB, 3, xB, b3_);

    f32x4 acc[4][4] = {};

    // prologue: tile0 complete {B0,A0,B1,A1}, tile1 partial {B0,A0,B1}; tile1.A1 comes at P1
    {
        const int k0 = kof(0), k1 = kof(1);
        SB(0, 0, k0); SA(0, 0, k0); SB(0, 1, k0); SA(0, 1, k0);
        SB(1, 0, k1); SA(1, 0, k1); SB(1, 1, k1);
    }
    VM(4);       // tile0's 6 done (only tile1's 4 newer)
    BARR;

    // one quad = 4 phases over one buffer; S1..S4 = per-phase stage units, VW = counted wait
#define QUAD(bb, S1, S2, S3, S4, VW)                                              \
    {                                                                             \
        { S1; }                                                                   \
        {                                                                         \
            bf16x8 b0 = BFRAG(bb, 0, 0), b1 = BFRAG(bb, 0, 1),                    \
                   b2 = BFRAG(bb, 0, 2), b3 = BFRAG(bb, 0, 3);                    \
            bf16x8 a0 = AFRAG(bb, 0, 0), a1 = AFRAG(bb, 0, 1);                    \
            BARR; PRIO1; M8(0, 1, a0, a1, b0, b1, b2, b3); PRIO0; BARR;           \
            { S2; }                                                               \
            bf16x8 a2 = AFRAG(bb, 0, 2), a3 = AFRAG(bb, 0, 3);                    \
            BARR; PRIO1; M8(2, 3, a2, a3, b0, b1, b2, b3); PRIO0; BARR;           \
        }                                                                         \
        { S3; }                                                                   \
        {                                                                         \
            bf16x8 b0 = BFRAG(bb, 1, 0), b1 = BFRAG(bb, 1, 1),                    \
                   b2 = BFRAG(bb, 1, 2), b3 = BFRAG(bb, 1, 3);                    \
            bf16x8 a0 = AFRAG(bb, 1, 0), a1 = AFRAG(bb, 1, 1);                    \
            BARR; PRIO1; M8(0, 1, a0, a1, b0, b1, b2, b3); PRIO0; BARR;           \
            { S4; }                                                               \
            bf16x8 a2 = AFRAG(bb, 1, 2), a3 = AFRAG(bb, 1, 3);                    \
            BARR; PRIO1; M8(2, 3, a2, a3, b0, b1, b2, b3); PRIO0;                 \
            { VW; }                                                               \
            BARR;                                                                 \
        }                                                                         \
    }

    for (int i = 0; i < NI; ++i) {
        const bool nl  = (i + 1 < NI);
        const int  kn1 = kof(2 * i + 1);
        const int  kn2 = nl ? kof(2 * i + 2) : 0;
        const int  kn3 = nl ? kof(2 * i + 3) : 0;

        // phases 1-4: tile t (buf0); stage t+1.A1, then t+2.{B0,A0,B1} -> buf0
        QUAD(0,
             SA(1, 1, kn1),
             if (nl) { SB(0, 0, kn2); },
             if (nl) { SA(0, 0, kn2); },
             if (nl) { SB(0, 1, kn2); },
             if (nl) { VM(4); } else { VM(0); });

        // phases 5-8: tile t+1 (buf1); stage t+2.A1 -> buf0, then t+3.{B0,A0,B1} -> buf1
        QUAD(1,
             if (nl) { SA(0, 1, kn2); },
             if (nl) { SB(1, 0, kn3); },
             if (nl) { SA(1, 0, kn3); },
             if (nl) { SB(1, 1, kn3); },
             if (nl) { VM(4); });
    }

    // epilogue: C/D layout col = lane&15, row = (lane>>4)*4 + reg  [m89-verified]
#pragma unroll
    for (int nt = 0; nt < 4; ++nt) {
        int n = n0 + wn + nt * 16 + fr;
        float bv = bias[n];
#pragma unroll
        for (int mt = 0; mt < 4; ++mt) {
            int m = m0 + wm + mt * 16 + fq * 4;
#pragma unroll
            for (int r = 0; r < 4; ++r)
                C[(size_t)(m + r) * NDIM + n] = acc[mt][nt][r] + bv;
        }
    }
}

extern "C" void kernel_launch(void* const* d_in, const int* in_sizes, int n_in,
                              void* d_out, int out_size, void* d_ws, size_t ws_size,
                              hipStream_t stream) {
    const float* x    = (const float*)d_in[0];   // [8192][3072]
    const float* w    = (const float*)d_in[1];   // [3072][1536]
    const float* bias = (const float*)d_in[2];   // [1536]
    const float* mask = (const float*)d_in[3];   // [1536][3072]
    float* out = (float*)d_out;                  // [8192][1536]

    u16* xb = (u16*)d_ws;                                   // 50331648 B
    u16* Bt = (u16*)((char*)d_ws + (size_t)50331648);       //  9437184 B

    static bool attr_done = false;
    if (!attr_done) {
        (void)hipFuncSetAttribute((const void*)gemm_kernel,
                                  hipFuncAttributeMaxDynamicSharedMemorySize, 98304);
        attr_done = true;
    }

    prep_kernel<<<NMB + NCVT, 256, 0, stream>>>(w, mask, Bt, (const float4*)x, (ushort4*)xb);
    gemm_kernel<<<NGB, 512, 98304, stream>>>(xb, Bt, bias, out);
}